// Round 1
// baseline (392.951 us; speedup 1.0000x reference)
//
#include <hip/hip_runtime.h>

// BiasAddLayerNormFP8: bda = residual + (x + bias); LayerNorm over H=1024;
// outputs: [bda2 f32 | fp8(ln) dequantized to f32 | amax scalar], all as float32.

constexpr int H = 1024;
constexpr float EPS = 1e-5f;
constexpr float FP8_MAX = 448.0f;
constexpr float INV_H = 1.0f / 1024.0f;

__device__ __forceinline__ float waveReduceSum(float v) {
#pragma unroll
    for (int off = 32; off > 0; off >>= 1) v += __shfl_down(v, off);
    return v;
}

__device__ __forceinline__ float waveReduceMax(float v) {
#pragma unroll
    for (int off = 32; off > 0; off >>= 1) v = fmaxf(v, __shfl_down(v, off));
    return v;
}

__global__ __launch_bounds__(256) void fused_bda_ln_fp8(
    const float* __restrict__ x,
    const float* __restrict__ bias,
    const float* __restrict__ residual,
    const float* __restrict__ gamma,
    const float* __restrict__ beta,
    float* __restrict__ out_bda,
    float* __restrict__ out_q,
    unsigned int* __restrict__ out_amax)
{
    const int row = blockIdx.x;
    const int tid = threadIdx.x;          // 256 threads, 4 waves
    const int lane = tid & 63;
    const int wid = tid >> 6;
    const int col = tid * 4;
    const size_t base = (size_t)row * H + col;

    __shared__ float red[4];

    // Load (float4 = 16B/lane, coalesced)
    const float4 xv = *reinterpret_cast<const float4*>(x + base);
    const float4 rv = *reinterpret_cast<const float4*>(residual + base);
    const float4 bv = *reinterpret_cast<const float4*>(bias + col);

    // bda = residual + (x + bias)  (match reference association)
    float b0 = rv.x + (xv.x + bv.x);
    float b1 = rv.y + (xv.y + bv.y);
    float b2 = rv.z + (xv.z + bv.z);
    float b3 = rv.w + (xv.w + bv.w);

    // Write bda2
    float4 bvout = make_float4(b0, b1, b2, b3);
    *reinterpret_cast<float4*>(out_bda + base) = bvout;

    // ---- pass 1: mean ----
    float s = (b0 + b1) + (b2 + b3);
    s = waveReduceSum(s);
    if (lane == 0) red[wid] = s;
    __syncthreads();
    const float mu = (red[0] + red[1] + red[2] + red[3]) * INV_H;

    // ---- pass 2: variance (two-pass, matches mean(square(bda-mu))) ----
    const float d0 = b0 - mu, d1 = b1 - mu, d2 = b2 - mu, d3 = b3 - mu;
    float ss = (d0 * d0 + d1 * d1) + (d2 * d2 + d3 * d3);
    ss = waveReduceSum(ss);
    __syncthreads();               // everyone done reading red[] from pass 1
    if (lane == 0) red[wid] = ss;
    __syncthreads();
    const float var = (red[0] + red[1] + red[2] + red[3]) * INV_H;
    const float rsigma = 1.0f / sqrtf(var + EPS);

    // ---- normalize + affine ----
    const float4 gv = *reinterpret_cast<const float4*>(gamma + col);
    const float4 tv = *reinterpret_cast<const float4*>(beta + col);
    const float l0 = d0 * rsigma * gv.x + tv.x;
    const float l1 = d1 * rsigma * gv.y + tv.y;
    const float l2 = d2 * rsigma * gv.z + tv.z;
    const float l3 = d3 * rsigma * gv.w + tv.w;

    // ---- amax (pre-clip |ln|) ----
    float m = fmaxf(fmaxf(fabsf(l0), fabsf(l1)), fmaxf(fabsf(l2), fabsf(l3)));

    // ---- fp8 e4m3fn quantize (clamp then HW RTNE convert), dequant to f32 ----
    const float c0 = fminf(fmaxf(l0, -FP8_MAX), FP8_MAX);
    const float c1 = fminf(fmaxf(l1, -FP8_MAX), FP8_MAX);
    const float c2 = fminf(fmaxf(l2, -FP8_MAX), FP8_MAX);
    const float c3 = fminf(fmaxf(l3, -FP8_MAX), FP8_MAX);
    const int p01 = __builtin_amdgcn_cvt_pk_fp8_f32(c0, c1, 0, false);
    const int p23 = __builtin_amdgcn_cvt_pk_fp8_f32(c2, c3, 0, false);
    float4 qv;
    qv.x = __builtin_amdgcn_cvt_f32_fp8(p01, 0);
    qv.y = __builtin_amdgcn_cvt_f32_fp8(p01, 1);
    qv.z = __builtin_amdgcn_cvt_f32_fp8(p23, 0);
    qv.w = __builtin_amdgcn_cvt_f32_fp8(p23, 1);
    *reinterpret_cast<float4*>(out_q + base) = qv;

    // ---- global amax: block reduce then one device-scope atomic ----
    m = waveReduceMax(m);
    __syncthreads();               // red[] reuse
    if (lane == 0) red[wid] = m;
    __syncthreads();
    if (tid == 0) {
        float bm = fmaxf(fmaxf(red[0], red[1]), fmaxf(red[2], red[3]));
        atomicMax(out_amax, __float_as_uint(bm));  // all values >= 0
    }
}

extern "C" void kernel_launch(void* const* d_in, const int* in_sizes, int n_in,
                              void* d_out, int out_size, void* d_ws, size_t ws_size,
                              hipStream_t stream) {
    const float* x        = (const float*)d_in[0];
    const float* bias     = (const float*)d_in[1];
    const float* residual = (const float*)d_in[2];
    const float* gamma    = (const float*)d_in[3];
    const float* beta     = (const float*)d_in[4];

    const int n_elems = in_sizes[0];          // B*S*H
    const int n_rows = n_elems / H;           // 32768

    float* out_bda = (float*)d_out;
    float* out_q   = out_bda + (size_t)n_elems;
    unsigned int* out_amax = (unsigned int*)(out_bda + 2 * (size_t)n_elems);

    // zero the amax slot each launch (deterministic across graph replays)
    hipMemsetAsync((void*)out_amax, 0, sizeof(unsigned int), stream);

    fused_bda_ln_fp8<<<n_rows, 256, 0, stream>>>(
        x, bias, residual, gamma, beta, out_bda, out_q, out_amax);
}

// Round 2
// 145.483 us; speedup vs baseline: 2.7010x; 2.7010x over previous
//
#include <hip/hip_runtime.h>

// BiasAddLayerNormFP8: bda = residual + (x + bias); LayerNorm over H=1024;
// outputs: [bda2 f32 | fp8(ln) dequantized to f32 | amax scalar], all as float32.
//
// Structure: one WAVE per row (no __syncthreads in row path), 16 floats/lane,
// grid-stride over rows with 2048 blocks x 4 waves -> 8 blocks/CU, 32 waves/CU.

constexpr int H = 1024;
constexpr int CHUNKS = 4;            // 4 x float4 x 64 lanes = 1024 cols
constexpr float EPS = 1e-5f;
constexpr float FP8_MAX = 448.0f;
constexpr float INV_H = 1.0f / 1024.0f;

__device__ __forceinline__ float waveAllReduceSum(float v) {
#pragma unroll
    for (int off = 1; off < 64; off <<= 1) v += __shfl_xor(v, off);
    return v;
}

__device__ __forceinline__ float waveReduceMax(float v) {
#pragma unroll
    for (int off = 32; off > 0; off >>= 1) v = fmaxf(v, __shfl_down(v, off));
    return v;
}

__global__ __launch_bounds__(256, 8) void fused_bda_ln_fp8(
    const float* __restrict__ x,
    const float* __restrict__ bias,
    const float* __restrict__ residual,
    const float* __restrict__ gamma,
    const float* __restrict__ beta,
    float* __restrict__ out_bda,
    float* __restrict__ out_q,
    unsigned int* __restrict__ out_amax,
    int n_rows)
{
    const int tid = threadIdx.x;      // 256 threads = 4 waves
    const int lane = tid & 63;
    const int wid = tid >> 6;
    const int col0 = lane * 4;        // lane's first column within chunk 0

    float localAmax = 0.0f;
    __shared__ float red[4];

#pragma unroll 1
    for (int row = blockIdx.x * 4 + wid; row < n_rows; row += gridDim.x * 4) {
        const size_t rbase = (size_t)row * H;

        float bda[CHUNKS][4];
        float s = 0.0f;

        // ---- load x, residual (8 outstanding float4 loads), bias from L1 ----
#pragma unroll
        for (int c = 0; c < CHUNKS; ++c) {
            const int col = col0 + c * 256;
            const float4 xv = *reinterpret_cast<const float4*>(x + rbase + col);
            const float4 rv = *reinterpret_cast<const float4*>(residual + rbase + col);
            const float4 bv = *reinterpret_cast<const float4*>(bias + col);
            bda[c][0] = rv.x + (xv.x + bv.x);
            bda[c][1] = rv.y + (xv.y + bv.y);
            bda[c][2] = rv.z + (xv.z + bv.z);
            bda[c][3] = rv.w + (xv.w + bv.w);
            *reinterpret_cast<float4*>(out_bda + rbase + col) =
                make_float4(bda[c][0], bda[c][1], bda[c][2], bda[c][3]);
            s += (bda[c][0] + bda[c][1]) + (bda[c][2] + bda[c][3]);
        }

        // ---- mean (wave-synchronous butterfly, no barrier) ----
        s = waveAllReduceSum(s);
        const float mu = s * INV_H;

        // ---- variance, two-pass (values live in registers) ----
        float ss = 0.0f;
#pragma unroll
        for (int c = 0; c < CHUNKS; ++c) {
#pragma unroll
            for (int j = 0; j < 4; ++j) {
                bda[c][j] -= mu;                 // now holds (bda - mu)
                ss += bda[c][j] * bda[c][j];
            }
        }
        ss = waveAllReduceSum(ss);
        const float rsigma = 1.0f / sqrtf(ss * INV_H + EPS);

        // ---- normalize + affine + fp8 quantize/dequant + store ----
#pragma unroll
        for (int c = 0; c < CHUNKS; ++c) {
            const int col = col0 + c * 256;
            const float4 gv = *reinterpret_cast<const float4*>(gamma + col);
            const float4 tv = *reinterpret_cast<const float4*>(beta + col);
            const float l0 = bda[c][0] * rsigma * gv.x + tv.x;
            const float l1 = bda[c][1] * rsigma * gv.y + tv.y;
            const float l2 = bda[c][2] * rsigma * gv.z + tv.z;
            const float l3 = bda[c][3] * rsigma * gv.w + tv.w;

            localAmax = fmaxf(localAmax,
                fmaxf(fmaxf(fabsf(l0), fabsf(l1)), fmaxf(fabsf(l2), fabsf(l3))));

            const float c0 = fminf(fmaxf(l0, -FP8_MAX), FP8_MAX);
            const float c1 = fminf(fmaxf(l1, -FP8_MAX), FP8_MAX);
            const float c2 = fminf(fmaxf(l2, -FP8_MAX), FP8_MAX);
            const float c3 = fminf(fmaxf(l3, -FP8_MAX), FP8_MAX);
            const int p01 = __builtin_amdgcn_cvt_pk_fp8_f32(c0, c1, 0, false);
            const int p23 = __builtin_amdgcn_cvt_pk_fp8_f32(c2, c3, 0, false);
            float4 qv;
            qv.x = __builtin_amdgcn_cvt_f32_fp8(p01, 0);
            qv.y = __builtin_amdgcn_cvt_f32_fp8(p01, 1);
            qv.z = __builtin_amdgcn_cvt_f32_fp8(p23, 0);
            qv.w = __builtin_amdgcn_cvt_f32_fp8(p23, 1);
            *reinterpret_cast<float4*>(out_q + rbase + col) = qv;
        }
    }

    // ---- block amax -> one device-scope atomic per block ----
    float m = waveReduceMax(localAmax);
    if (lane == 0) red[wid] = m;
    __syncthreads();
    if (tid == 0) {
        const float bm = fmaxf(fmaxf(red[0], red[1]), fmaxf(red[2], red[3]));
        atomicMax(out_amax, __float_as_uint(bm));   // all values >= 0
    }
}

extern "C" void kernel_launch(void* const* d_in, const int* in_sizes, int n_in,
                              void* d_out, int out_size, void* d_ws, size_t ws_size,
                              hipStream_t stream) {
    const float* x        = (const float*)d_in[0];
    const float* bias     = (const float*)d_in[1];
    const float* residual = (const float*)d_in[2];
    const float* gamma    = (const float*)d_in[3];
    const float* beta     = (const float*)d_in[4];

    const int n_elems = in_sizes[0];          // B*S*H
    const int n_rows = n_elems / H;           // 32768

    float* out_bda = (float*)d_out;
    float* out_q   = out_bda + (size_t)n_elems;
    unsigned int* out_amax = (unsigned int*)(out_bda + 2 * (size_t)n_elems);

    // zero the amax slot each launch (deterministic across graph replays)
    hipMemsetAsync((void*)out_amax, 0, sizeof(unsigned int), stream);

    int blocks = (n_rows + 3) / 4;
    if (blocks > 2048) blocks = 2048;         // 8 blocks/CU, grid-stride the rest

    fused_bda_ln_fp8<<<blocks, 256, 0, stream>>>(
        x, bias, residual, gamma, beta, out_bda, out_q, out_amax, n_rows);
}